// Round 9
// baseline (308.022 us; speedup 1.0000x reference)
//
#include <hip/hip_runtime.h>
#include <hip/hip_bf16.h>
#include <cstdint>
#include <cstddef>

// B=4, T=256, U=64, H=512, K=512, V=1024; M = 65536 rows, log_softmax over V.
// Round 9: PERSISTENT blocks (256 blocks x 4 tiles of BM=64), 1024 thr =
// 16 waves, wave tile 64x64 (acc 64 f32). B direct from L2-resident w2st,
// depth-2 P/Q register prefetch (no copies). Raw s_barrier+lgkmcnt only in
// the tile loop (no vmcnt(0) drains); stores of tile t hide under tile t+1;
// next tile's first 2 chunks issued BEFORE stores (vmcnt is in-order).

typedef __attribute__((ext_vector_type(8))) short short8;
typedef __attribute__((ext_vector_type(4))) float f32x4;

#define BS_CHUNK 65536                // one BK=32 chunk of W2 image: 1024 cols * 64 B

// ws layout
#define WS_EP_OFF 0                           // 1024*512 f32 = 2 MiB
#define WS_DP_OFF (1024 * 512 * 4)            // 256*512 f32 = 512 KiB
#define WS_W2_OFF (WS_DP_OFF + 256 * 512 * 4) // W2 bf16 image: 16 chunks * 64 KiB

// joint LDS: A 64 KiB + redM 4K + redF 256 + redS 4K + redF2 256
#define SMEM_TOTAL (65536 + 4096 + 256 + 4096 + 256)

// raw barrier: commit my ds_writes, rendezvous. NO vmcnt drain.
#define BAR()                                                   \
  do {                                                          \
    asm volatile("s_waitcnt lgkmcnt(0)" ::: "memory");          \
    __builtin_amdgcn_s_barrier();                               \
    __builtin_amdgcn_sched_barrier(0);                          \
  } while (0)

__device__ __forceinline__ unsigned short f2bf(float x) {
  unsigned int u = __builtin_bit_cast(unsigned int, x);
  u += 0x7FFFu + ((u >> 16) & 1u);
  return (unsigned short)(u >> 16);
}

__device__ __forceinline__ float fast_tanh(float x) {
  float ax = fabsf(x);
  float e = __expf(-2.0f * ax);
  float t = (1.0f - e) * __builtin_amdgcn_rcpf(1.0f + e);
  return copysignf(t, x);
}

// ---------------------------------------------------------------------------
// prep (fused): blocks 0..159 -> ep/dp projections (8 rows each);
//               blocks 160..191 -> W2 repack to bf16 image:
//   w2st[kc*65536 + v*64 + ki*2] = bf16(W2[kc*32+ki][v])
// ---------------------------------------------------------------------------
__global__ __launch_bounds__(512) void prep(
    const float* __restrict__ enc, const float* __restrict__ dec,
    const float* __restrict__ W1, const float* __restrict__ b1,
    const float* __restrict__ W2,
    float* __restrict__ ep, float* __restrict__ dp, char* __restrict__ w2st) {
  __shared__ float As[8 * 512];
  const int tid = threadIdx.x;
  if (blockIdx.x < 160) {
    const int r0 = blockIdx.x * 8;
    const bool isenc = (r0 < 1024);
    const float* A = isenc ? (enc + (size_t)r0 * 512) : (dec + (size_t)(r0 - 1024) * 512);
    const float* W = isenc ? W1 : (W1 + 512 * 512);
    float* O = isenc ? (ep + (size_t)r0 * 512) : (dp + (size_t)(r0 - 1024) * 512);

    for (int idx = tid; idx < 8 * 512; idx += 512) As[idx] = A[idx];
    __syncthreads();

    const int c = tid;
    float acc[8];
#pragma unroll
    for (int r = 0; r < 8; ++r) acc[r] = 0.0f;
    const float4* As4 = (const float4*)As;
#pragma unroll 2
    for (int k4 = 0; k4 < 128; ++k4) {
      const int kb = k4 * 4;
      float w0 = W[(size_t)(kb + 0) * 512 + c];
      float w1 = W[(size_t)(kb + 1) * 512 + c];
      float w2 = W[(size_t)(kb + 2) * 512 + c];
      float w3 = W[(size_t)(kb + 3) * 512 + c];
#pragma unroll
      for (int r = 0; r < 8; ++r) {
        float4 a = As4[r * 128 + k4];
        acc[r] += a.x * w0 + a.y * w1 + a.z * w2 + a.w * w3;
      }
    }
    const float bias = isenc ? b1[c] : 0.0f;
#pragma unroll
    for (int r = 0; r < 8; ++r) O[(size_t)r * 512 + c] = acc[r] + bias;
  } else {
    const int g = (blockIdx.x - 160) * 512 + tid;  // 0..16383
    const int v = g & 1023;
    const int kc = g >> 10;
    unsigned short vals[32];
#pragma unroll
    for (int ki = 0; ki < 32; ++ki)
      vals[ki] = f2bf(W2[(size_t)(kc * 32 + ki) * 1024 + v]);
    uint4* dst = (uint4*)(w2st + (size_t)kc * BS_CHUNK + (size_t)v * 64);
    const uint4* s = (const uint4*)vals;
    dst[0] = s[0]; dst[1] = s[1]; dst[2] = s[2]; dst[3] = s[3];
  }
}

// ---------------------------------------------------------------------------
// joint: persistent. Block bid processes tiles bt = bid*4 + t, t=0..3.
// Per tile: 64 rows x V=1024, 16 waves; wave w owns all 64 rows x cols
// [w*64, w*64+64): 4 m-frags x 4 n-frags, acc 64 f32.
// ---------------------------------------------------------------------------
__global__ __launch_bounds__(1024, 4) void joint(
    const float* __restrict__ ep, const float* __restrict__ dp,
    const char* __restrict__ w2st, const float* __restrict__ b2,
    float* __restrict__ out) {
  extern __shared__ char smem[];
  char* As = smem;                           // [64 rows][1024 B], XOR-swizzled
  float* redM = (float*)(smem + 65536);      // [16 waves][64 rows]
  float* redF = redM + 1024;                 // [64]
  float* redS = redF + 64;                   // [16][64]
  float* redF2 = redS + 1024;                // [64]

  const int tid = threadIdx.x;
  const int wave = tid >> 6, lane = tid & 63;
  const int lo = lane & 15, hi = lane >> 4;
  const int nbase = wave * 64;
  const char* bbase = w2st + (size_t)(nbase + lo) * 64 + hi * 16;

  float b2v[4];
#pragma unroll
  for (int ni = 0; ni < 4; ++ni) b2v[ni] = b2[nbase + ni * 16 + lo];

  short8 P[4], Q[4];
  // initial prefetch: tile 0's chunks rot(0), rot(1)
  {
    const int bt0 = blockIdx.x * 4;
    const int kr = bt0 & 15;
    const char* s0 = bbase + (size_t)kr * BS_CHUNK;
    const char* s1 = bbase + (size_t)((kr + 1) & 15) * BS_CHUNK;
#pragma unroll
    for (int ni = 0; ni < 4; ++ni) P[ni] = *(const short8*)(s0 + ni * 1024);
#pragma unroll
    for (int ni = 0; ni < 4; ++ni) Q[ni] = *(const short8*)(s1 + ni * 1024);
  }

#pragma unroll 1
  for (int t = 0; t < 4; ++t) {
    const int bt = blockIdx.x * 4 + t;
    const int m0 = bt * 64;
    const int dprow0 = (bt >> 8) * 64;
    const int krot = bt & 15;

    // -- tanh phase: A[64][512] -> bf16 LDS, addr ^ ((row&7)<<4) --
    {
      const int c0 = (tid & 63) * 8;
      const int rg = tid >> 6;               // rows rg, rg+16, rg+32, rg+48
      const float* epr = ep + (size_t)bt * 512 + c0;
      float e0[8];
      *(float4*)(e0) = *(const float4*)(epr);
      *(float4*)(e0 + 4) = *(const float4*)(epr + 4);
#pragma unroll
      for (int p = 0; p < 4; ++p) {
        const int row = rg + p * 16;
        const float* dpr = dp + (size_t)(dprow0 + row) * 512 + c0;
        float d0[8];
        *(float4*)(d0) = *(const float4*)(dpr);
        *(float4*)(d0 + 4) = *(const float4*)(dpr + 4);
        unsigned short h[8];
#pragma unroll
        for (int j = 0; j < 8; ++j) h[j] = f2bf(fast_tanh(e0[j] + d0[j]));
        *(uint4*)(As + ((row * 1024 + c0 * 2) ^ ((row & 7) << 4))) = *(const uint4*)h;
      }
    }

    f32x4 acc[4][4];
#pragma unroll
    for (int mi = 0; mi < 4; ++mi)
#pragma unroll
      for (int ni = 0; ni < 4; ++ni)
#pragma unroll
        for (int j = 0; j < 4; ++j) acc[mi][ni][j] = 0.0f;

    BAR();  // A visible

    // -- K loop: 8 pairs of chunks, depth-2 P/Q alternation --
#pragma unroll 1
    for (int i = 0; i < 8; ++i) {
      const int c0 = (2 * i + krot) & 15;
      const int c1 = (c0 + 1) & 15;
      {
        short8 a[4];
#pragma unroll
        for (int mi = 0; mi < 4; ++mi) {
          const int row = mi * 16 + lo;
          a[mi] = *(const short8*)(As + ((row * 1024 + c0 * 64 + hi * 16) ^ ((row & 7) << 4)));
        }
#pragma unroll
        for (int ni = 0; ni < 4; ++ni)
#pragma unroll
          for (int mi = 0; mi < 4; ++mi)
            acc[mi][ni] = __builtin_amdgcn_mfma_f32_16x16x32_bf16(a[mi], P[ni], acc[mi][ni], 0, 0, 0);
      }
      if (i < 7) {  // reload P with chunk c0+2 (consumed next pair)
        const char* src = bbase + (size_t)((c0 + 2) & 15) * BS_CHUNK;
#pragma unroll
        for (int ni = 0; ni < 4; ++ni) P[ni] = *(const short8*)(src + ni * 1024);
      }
      {
        short8 a[4];
#pragma unroll
        for (int mi = 0; mi < 4; ++mi) {
          const int row = mi * 16 + lo;
          a[mi] = *(const short8*)(As + ((row * 1024 + c1 * 64 + hi * 16) ^ ((row & 7) << 4)));
        }
#pragma unroll
        for (int ni = 0; ni < 4; ++ni)
#pragma unroll
          for (int mi = 0; mi < 4; ++mi)
            acc[mi][ni] = __builtin_amdgcn_mfma_f32_16x16x32_bf16(a[mi], Q[ni], acc[mi][ni], 0, 0, 0);
      }
      if (i < 7) {  // reload Q with chunk c1+2
        const char* src = bbase + (size_t)((c1 + 2) & 15) * BS_CHUNK;
#pragma unroll
        for (int ni = 0; ni < 4; ++ni) Q[ni] = *(const short8*)(src + ni * 1024);
      }
    }

    // -- epilogue: +b2, log_softmax over V, store --
#pragma unroll
    for (int mi = 0; mi < 4; ++mi)
#pragma unroll
      for (int ni = 0; ni < 4; ++ni)
#pragma unroll
        for (int j = 0; j < 4; ++j) acc[mi][ni][j] += b2v[ni];

    float pm[4][4];
#pragma unroll
    for (int mi = 0; mi < 4; ++mi)
#pragma unroll
      for (int r = 0; r < 4; ++r)
        pm[mi][r] = fmaxf(fmaxf(acc[mi][0][r], acc[mi][1][r]),
                          fmaxf(acc[mi][2][r], acc[mi][3][r]));
#pragma unroll
    for (int off = 1; off < 16; off <<= 1)
#pragma unroll
      for (int mi = 0; mi < 4; ++mi)
#pragma unroll
        for (int r = 0; r < 4; ++r)
          pm[mi][r] = fmaxf(pm[mi][r], __shfl_xor(pm[mi][r], off));
    if (lo == 0) {
#pragma unroll
      for (int mi = 0; mi < 4; ++mi)
#pragma unroll
        for (int r = 0; r < 4; ++r)
          redM[wave * 64 + mi * 16 + hi * 4 + r] = pm[mi][r];
    }
    BAR();
    {
      const int tr = tid >> 4, w = tid & 15;
      float v = redM[w * 64 + tr];
#pragma unroll
      for (int off = 1; off < 16; off <<= 1) v = fmaxf(v, __shfl_xor(v, off));
      if (w == 0) redF[tr] = v;
    }
    BAR();
    float rm[4][4];
#pragma unroll
    for (int mi = 0; mi < 4; ++mi)
#pragma unroll
      for (int r = 0; r < 4; ++r) rm[mi][r] = redF[mi * 16 + hi * 4 + r];

    float ps[4][4];
#pragma unroll
    for (int mi = 0; mi < 4; ++mi)
#pragma unroll
      for (int r = 0; r < 4; ++r) {
        float s = 0.0f;
#pragma unroll
        for (int ni = 0; ni < 4; ++ni) s += __expf(acc[mi][ni][r] - rm[mi][r]);
        ps[mi][r] = s;
      }
#pragma unroll
    for (int off = 1; off < 16; off <<= 1)
#pragma unroll
      for (int mi = 0; mi < 4; ++mi)
#pragma unroll
        for (int r = 0; r < 4; ++r)
          ps[mi][r] += __shfl_xor(ps[mi][r], off);
    if (lo == 0) {
#pragma unroll
      for (int mi = 0; mi < 4; ++mi)
#pragma unroll
        for (int r = 0; r < 4; ++r)
          redS[wave * 64 + mi * 16 + hi * 4 + r] = ps[mi][r];
    }
    BAR();
    {
      const int tr = tid >> 4, w = tid & 15;
      float v = redS[w * 64 + tr];
#pragma unroll
      for (int off = 1; off < 16; off <<= 1) v += __shfl_xor(v, off);
      if (w == 0) redF2[tr] = v;
    }
    BAR();

    // issue next tile's first two chunks BEFORE stores (loads precede stores
    // in vmcnt order -> their waits never force store retirement)
    if (t < 3) {
      const int nrot = (bt + 1) & 15;
      const char* s0 = bbase + (size_t)nrot * BS_CHUNK;
      const char* s1 = bbase + (size_t)((nrot + 1) & 15) * BS_CHUNK;
#pragma unroll
      for (int ni = 0; ni < 4; ++ni) P[ni] = *(const short8*)(s0 + ni * 1024);
#pragma unroll
      for (int ni = 0; ni < 4; ++ni) Q[ni] = *(const short8*)(s1 + ni * 1024);
    }

#pragma unroll
    for (int mi = 0; mi < 4; ++mi)
#pragma unroll
      for (int r = 0; r < 4; ++r) {
        const int row = mi * 16 + hi * 4 + r;
        const float sub = rm[mi][r] + __logf(redF2[row]);
        float* op = out + (size_t)(m0 + row) * 1024 + nbase + lo;
#pragma unroll
        for (int ni = 0; ni < 4; ++ni) op[ni * 16] = acc[mi][ni][r] - sub;
      }
  }
}

// ---------------------------------------------------------------------------
extern "C" void kernel_launch(void* const* d_in, const int* in_sizes, int n_in,
                              void* d_out, int out_size, void* d_ws, size_t ws_size,
                              hipStream_t stream) {
  const float* enc = (const float*)d_in[0];
  const float* dec = (const float*)d_in[1];
  const float* W1  = (const float*)d_in[2];
  const float* b1  = (const float*)d_in[3];
  const float* W2  = (const float*)d_in[4];
  const float* b2  = (const float*)d_in[5];
  float* out = (float*)d_out;

  char* ws = (char*)d_ws;
  float* ep = (float*)(ws + WS_EP_OFF);
  float* dp = (float*)(ws + WS_DP_OFF);
  char* w2st = ws + WS_W2_OFF;

  prep<<<192, 512, 0, stream>>>(enc, dec, W1, b1, W2, ep, dp, w2st);
  joint<<<256, 1024, SMEM_TOTAL, stream>>>(ep, dp, w2st, b2, out);
}

// Round 10
// 257.536 us; speedup vs baseline: 1.1960x; 1.1960x over previous
//
#include <hip/hip_runtime.h>
#include <hip/hip_bf16.h>
#include <cstdint>
#include <cstddef>

// B=4, T=256, U=64, H=512, K=512, V=1024; M = 65536 rows, log_softmax over V.
// Round 10: T3+T4 pipeline. Block = 64 rows x V=1024, 1024 thr = 16 waves,
// wave tile 64x64 (acc 64 f32). B chunks (BK=32, 64 KB) staged via
// global_load_lds into a DOUBLE buffer; counted s_waitcnt vmcnt(4) keeps 2
// chunks in flight across barriers (never vmcnt(0) mid-loop). A is a
// quarter-K panel [64][128] bf16 (16 KB) recomputed by tanh every 4 chunks.
// LDS = 16K (A) + 2x64K (B) = 144 KB; reductions alias A post-loop.

typedef __attribute__((ext_vector_type(8))) short short8;
typedef __attribute__((ext_vector_type(4))) float f32x4;

#define BS_CHUNK 65536                // one BK=32 chunk of W2 image: 1024 cols * 64 B

// ws layout
#define WS_EP_OFF 0                           // 1024*512 f32 = 2 MiB
#define WS_DP_OFF (1024 * 512 * 4)            // 256*512 f32 = 512 KiB
#define WS_W2_OFF (WS_DP_OFF + 256 * 512 * 4) // W2 bf16 image: 16 chunks * 64 KiB

#define LDS_B0 16384
#define LDS_B1 81920
#define SMEM_TOTAL 147456                     // 144 KiB

__device__ __forceinline__ unsigned short f2bf(float x) {
  unsigned int u = __builtin_bit_cast(unsigned int, x);
  u += 0x7FFFu + ((u >> 16) & 1u);
  return (unsigned short)(u >> 16);
}

__device__ __forceinline__ float fast_tanh(float x) {
  float ax = fabsf(x);
  float e = __expf(-2.0f * ax);
  float t = (1.0f - e) * __builtin_amdgcn_rcpf(1.0f + e);
  return copysignf(t, x);
}

// ---------------------------------------------------------------------------
// prep (fused): blocks 0..319 -> ep/dp projections (4 rows each);
//               blocks 320..351 -> W2 repack to bf16 image:
//   w2st[kc*65536 + v*64 + ki*2] = bf16(W2[kc*32+ki][v])
// ---------------------------------------------------------------------------
__global__ __launch_bounds__(512) void prep(
    const float* __restrict__ enc, const float* __restrict__ dec,
    const float* __restrict__ W1, const float* __restrict__ b1,
    const float* __restrict__ W2,
    float* __restrict__ ep, float* __restrict__ dp, char* __restrict__ w2st) {
  __shared__ float As[4 * 512];
  const int tid = threadIdx.x;
  if (blockIdx.x < 320) {
    const int r0 = blockIdx.x * 4;
    const bool isenc = (r0 < 1024);
    const float* A = isenc ? (enc + (size_t)r0 * 512) : (dec + (size_t)(r0 - 1024) * 512);
    const float* W = isenc ? W1 : (W1 + 512 * 512);
    float* O = isenc ? (ep + (size_t)r0 * 512) : (dp + (size_t)(r0 - 1024) * 512);

    for (int idx = tid; idx < 4 * 512; idx += 512) As[idx] = A[idx];
    __syncthreads();

    const int c = tid;
    float acc[4] = {0.f, 0.f, 0.f, 0.f};
    const float4* As4 = (const float4*)As;
#pragma unroll 4
    for (int k4 = 0; k4 < 128; ++k4) {
      const int kb = k4 * 4;
      float w0 = W[(size_t)(kb + 0) * 512 + c];
      float w1 = W[(size_t)(kb + 1) * 512 + c];
      float w2 = W[(size_t)(kb + 2) * 512 + c];
      float w3 = W[(size_t)(kb + 3) * 512 + c];
#pragma unroll
      for (int r = 0; r < 4; ++r) {
        float4 a = As4[r * 128 + k4];
        acc[r] += a.x * w0 + a.y * w1 + a.z * w2 + a.w * w3;
      }
    }
    const float bias = isenc ? b1[c] : 0.0f;
#pragma unroll
    for (int r = 0; r < 4; ++r) O[(size_t)r * 512 + c] = acc[r] + bias;
  } else {
    const int g = (blockIdx.x - 320) * 512 + tid;  // 0..16383
    const int v = g & 1023;
    const int kc = g >> 10;
    unsigned short vals[32];
#pragma unroll
    for (int ki = 0; ki < 32; ++ki)
      vals[ki] = f2bf(W2[(size_t)(kc * 32 + ki) * 1024 + v]);
    uint4* dst = (uint4*)(w2st + (size_t)kc * BS_CHUNK + (size_t)v * 64);
    const uint4* s = (const uint4*)vals;
    dst[0] = s[0]; dst[1] = s[1]; dst[2] = s[2]; dst[3] = s[3];
  }
}

// ---------------------------------------------------------------------------
__device__ __forceinline__ void stage_chunk(const char* __restrict__ w2st,
                                            char* dstbuf, int gc, int wave, int lane) {
  const char* src = w2st + (size_t)gc * BS_CHUNK + wave * 4096 + (size_t)lane * 16;
  char* dst = dstbuf + wave * 4096 + lane * 16;
#pragma unroll
  for (int jj = 0; jj < 4; ++jj)
    __builtin_amdgcn_global_load_lds(
        (const __attribute__((address_space(1))) unsigned int*)(src + jj * 1024),
        (__attribute__((address_space(3))) unsigned int*)(dst + jj * 1024), 16, 0, 0);
}

// joint: block = 64 rows (one (b,t)) x V=1024; 16 waves; wave w owns all 64
// rows x cols [w*64, w*64+64): 4 m-frags x 4 n-frags.
__global__ __launch_bounds__(1024, 4) void joint(
    const float* __restrict__ ep, const float* __restrict__ dp,
    const char* __restrict__ w2st, const float* __restrict__ b2,
    float* __restrict__ out) {
  extern __shared__ char smem[];
  char* Asm = smem;                           // [64 rows][256 B] quarter-K panel
  float* redM = (float*)smem;                 // aliases A after the K-loop
  float* redF = redM + 1024;
  float* redS = redF + 64;
  float* redF2 = redS + 1024;

  const int tid = threadIdx.x;
  const int wave = tid >> 6, lane = tid & 63;
  const int lo = lane & 15, hi = lane >> 4;
  const int bt = blockIdx.x;
  const int m0 = bt * 64;
  const int dprow0 = (bt >> 8) * 64;
  const int nbase = wave * 64;
  const int krot4 = bt & 3;

  const int tr = tid >> 4;                    // tanh row 0..63
  const int tc = (tid & 15) * 8;              // tanh col-in-quarter

  float b2v[4];
#pragma unroll
  for (int ni = 0; ni < 4; ++ni) b2v[ni] = b2[nbase + ni * 16 + lo];

  // prologue: q0 tanh loads BEFORE stages -> compiler's wait for tanh data
  // leaves the 8 stage loads in flight.
  float e0[8], d0[8];
  {
    const float* epr = ep + (size_t)bt * 512 + tc;
    *(float4*)(e0) = ((const float4*)epr)[0];
    *(float4*)(e0 + 4) = ((const float4*)epr)[1];
    const float* dpr = dp + (size_t)(dprow0 + tr) * 512 + tc;
    *(float4*)(d0) = ((const float4*)dpr)[0];
    *(float4*)(d0 + 4) = ((const float4*)dpr)[1];
  }
  stage_chunk(w2st, smem + LDS_B0, (0 + krot4) & 3, wave, lane);
  stage_chunk(w2st, smem + LDS_B1, (1 + krot4) & 3, wave, lane);
  __builtin_amdgcn_sched_barrier(0);
  {
    unsigned short h[8];
#pragma unroll
    for (int j = 0; j < 8; ++j) h[j] = f2bf(fast_tanh(e0[j] + d0[j]));
    *(uint4*)(Asm + ((tr * 256 + tc * 2) ^ ((tr & 7) << 4))) = *(const uint4*)h;
  }

  f32x4 acc[4][4];
#pragma unroll
  for (int mi = 0; mi < 4; ++mi)
#pragma unroll
    for (int ni = 0; ni < 4; ++ni)
#pragma unroll
      for (int j = 0; j < 4; ++j) acc[mi][ni][j] = 0.0f;

#pragma unroll
  for (int q = 0; q < 4; ++q) {
    if (q) {  // recompute A panel for quarter q (prev reads done at barB)
      const float* epr = ep + (size_t)bt * 512 + q * 128 + tc;
      float e1[8], d1[8];
      *(float4*)(e1) = ((const float4*)epr)[0];
      *(float4*)(e1 + 4) = ((const float4*)epr)[1];
      const float* dpr = dp + (size_t)(dprow0 + tr) * 512 + q * 128 + tc;
      *(float4*)(d1) = ((const float4*)dpr)[0];
      *(float4*)(d1 + 4) = ((const float4*)dpr)[1];
      unsigned short h[8];
#pragma unroll
      for (int j = 0; j < 8; ++j) h[j] = f2bf(fast_tanh(e1[j] + d1[j]));
      *(uint4*)(Asm + ((tr * 256 + tc * 2) ^ ((tr & 7) << 4))) = *(const uint4*)h;
    }
#pragma unroll
    for (int ii = 0; ii < 4; ++ii) {
      const int i = q * 4 + ii;
      if (i == 15) asm volatile("s_waitcnt vmcnt(0) lgkmcnt(0)" ::: "memory");
      else         asm volatile("s_waitcnt vmcnt(4) lgkmcnt(0)" ::: "memory");
      __builtin_amdgcn_s_barrier();           // barrier A: chunk i resident
      __builtin_amdgcn_sched_barrier(0);

      char* rdbuf = smem + ((i & 1) ? LDS_B1 : LDS_B0);
      const int cif = (i + krot4) & 3;
      short8 bfr[4], afr[4];
      const char* bp = rdbuf + (size_t)(nbase + lo) * 64 + hi * 16;
#pragma unroll
      for (int ni = 0; ni < 4; ++ni) bfr[ni] = *(const short8*)(bp + ni * 1024);
#pragma unroll
      for (int mi = 0; mi < 4; ++mi) {
        const int row = mi * 16 + lo;
        afr[mi] = *(const short8*)(Asm + ((row * 256 + cif * 64 + hi * 16) ^ ((row & 7) << 4)));
      }
      asm volatile("s_waitcnt lgkmcnt(0)" ::: "memory");
      __builtin_amdgcn_sched_barrier(0);
      __builtin_amdgcn_s_barrier();           // barrier B: all reads done
      __builtin_amdgcn_sched_barrier(0);

      if (i < 14) {
        const int j = i + 2;
        const int gc = (j >> 2) * 4 + ((j + krot4) & 3);
        stage_chunk(w2st, rdbuf, gc, wave, lane);
        __builtin_amdgcn_sched_barrier(0);
      }
#pragma unroll
      for (int ni = 0; ni < 4; ++ni)
#pragma unroll
        for (int mi = 0; mi < 4; ++mi)
          acc[mi][ni] = __builtin_amdgcn_mfma_f32_16x16x32_bf16(afr[mi], bfr[ni], acc[mi][ni], 0, 0, 0);
    }
  }

  // epilogue: +b2, log_softmax, store (reds alias A region)
#pragma unroll
  for (int mi = 0; mi < 4; ++mi)
#pragma unroll
    for (int ni = 0; ni < 4; ++ni)
#pragma unroll
      for (int j = 0; j < 4; ++j) acc[mi][ni][j] += b2v[ni];

  float pm[4][4];
#pragma unroll
  for (int mi = 0; mi < 4; ++mi)
#pragma unroll
    for (int r = 0; r < 4; ++r)
      pm[mi][r] = fmaxf(fmaxf(acc[mi][0][r], acc[mi][1][r]),
                        fmaxf(acc[mi][2][r], acc[mi][3][r]));
#pragma unroll
  for (int off = 1; off < 16; off <<= 1)
#pragma unroll
    for (int mi = 0; mi < 4; ++mi)
#pragma unroll
      for (int r = 0; r < 4; ++r)
        pm[mi][r] = fmaxf(pm[mi][r], __shfl_xor(pm[mi][r], off));
  if (lo == 0) {
#pragma unroll
    for (int mi = 0; mi < 4; ++mi)
#pragma unroll
      for (int r = 0; r < 4; ++r)
        redM[wave * 64 + mi * 16 + hi * 4 + r] = pm[mi][r];
  }
  asm volatile("s_waitcnt lgkmcnt(0)" ::: "memory");
  __builtin_amdgcn_s_barrier();
  {
    const int rr = tid >> 4, w = tid & 15;
    float v = redM[w * 64 + rr];
#pragma unroll
    for (int off = 1; off < 16; off <<= 1) v = fmaxf(v, __shfl_xor(v, off));
    if (w == 0) redF[rr] = v;
  }
  asm volatile("s_waitcnt lgkmcnt(0)" ::: "memory");
  __builtin_amdgcn_s_barrier();
  float rm[4][4];
#pragma unroll
  for (int mi = 0; mi < 4; ++mi)
#pragma unroll
    for (int r = 0; r < 4; ++r) rm[mi][r] = redF[mi * 16 + hi * 4 + r];

  float ps[4][4];
#pragma unroll
  for (int mi = 0; mi < 4; ++mi)
#pragma unroll
    for (int r = 0; r < 4; ++r) {
      float s = 0.0f;
#pragma unroll
      for (int ni = 0; ni < 4; ++ni) s += __expf(acc[mi][ni][r] - rm[mi][r]);
      ps[mi][r] = s;
    }
#pragma unroll
  for (int off = 1; off < 16; off <<= 1)
#pragma unroll
    for (int mi = 0; mi < 4; ++mi)
#pragma unroll
      for (int r = 0; r < 4; ++r)
        ps[mi][r] += __shfl_xor(ps[mi][r], off);
  if (lo == 0) {
#pragma unroll
    for (int mi = 0; mi < 4; ++mi)
#pragma unroll
      for (int r = 0; r < 4; ++r)
        redS[wave * 64 + mi * 16 + hi * 4 + r] = ps[mi][r];
  }
  asm volatile("s_waitcnt lgkmcnt(0)" ::: "memory");
  __builtin_amdgcn_s_barrier();
  {
    const int rr = tid >> 4, w = tid & 15;
    float v = redS[w * 64 + rr];
#pragma unroll
    for (int off = 1; off < 16; off <<= 1) v += __shfl_xor(v, off);
    if (w == 0) redF2[rr] = v;
  }
  asm volatile("s_waitcnt lgkmcnt(0)" ::: "memory");
  __builtin_amdgcn_s_barrier();

#pragma unroll
  for (int mi = 0; mi < 4; ++mi)
#pragma unroll
    for (int r = 0; r < 4; ++r) {
      const int row = mi * 16 + hi * 4 + r;
      const float sub = rm[mi][r] + __logf(redF2[row]);
      float* op = out + (size_t)(m0 + row) * 1024 + nbase + lo;
#pragma unroll
      for (int ni = 0; ni < 4; ++ni) op[ni * 16] = acc[mi][ni][r] - sub;
    }
}

// ---------------------------------------------------------------------------
extern "C" void kernel_launch(void* const* d_in, const int* in_sizes, int n_in,
                              void* d_out, int out_size, void* d_ws, size_t ws_size,
                              hipStream_t stream) {
  const float* enc = (const float*)d_in[0];
  const float* dec = (const float*)d_in[1];
  const float* W1  = (const float*)d_in[2];
  const float* b1  = (const float*)d_in[3];
  const float* W2  = (const float*)d_in[4];
  const float* b2  = (const float*)d_in[5];
  float* out = (float*)d_out;

  char* ws = (char*)d_ws;
  float* ep = (float*)(ws + WS_EP_OFF);
  float* dp = (float*)(ws + WS_DP_OFF);
  char* w2st = ws + WS_W2_OFF;

  prep<<<352, 512, 0, stream>>>(enc, dec, W1, b1, W2, ep, dp, w2st);
  joint<<<1024, 1024, SMEM_TOTAL, stream>>>(ep, dp, w2st, b2, out);
}